// Round 10
// baseline (50.407 us; speedup 1.0000x reference)
//
#include <hip/hip_runtime.h>
#include <stdint.h>

#define N_TOTAL 4096
#define DIMS 256
#define M_HALF 2048
#define NNEIGH 30
#define NTILES 1024   // (4096/128)^2
#define NSLICE 32     // one den partial per bn

typedef __bf16 bf16_t;
typedef bf16_t bf16x8 __attribute__((ext_vector_type(8)));
typedef float f32x4 __attribute__((ext_vector_type(4)));
typedef uint32_t u32x4 __attribute__((ext_vector_type(4)));

__device__ inline uint16_t f2bf(float f) {
    union { float f; uint32_t u; } v; v.f = f;
    uint32_t u = v.u;
    uint32_t r = (u + 0x7fffu + ((u >> 16) & 1u)) >> 16;  // RNE
    return (uint16_t)r;
}

// Normalize + transpose: emb[16][256 d][256 l] f32 -> F[4096 r][256 d] bf16.
__global__ __launch_bounds__(256) void nt_kernel(const float* __restrict__ emb,
                                                 uint16_t* __restrict__ F) {
    __shared__ float tile[16][257];
    __shared__ float invn[16];
    const int bi = blockIdx.x >> 4;
    const int lc = blockIdx.x & 15;
    const int l0 = lc * 16;
    const int tid = threadIdx.x;
    const float* src = emb + (size_t)bi * DIMS * 256 + l0;
    #pragma unroll
    for (int p = 0; p < 16; ++p) {
        int idx = p * 256 + tid;
        int l = idx & 15;
        int d = idx >> 4;
        tile[l][d] = src[(size_t)d * 256 + l];
    }
    __syncthreads();
    {
        int l = tid >> 4;
        int c = tid & 15;
        float ss = 0.f;
        #pragma unroll
        for (int d = 0; d < 256; d += 16) {
            float v = tile[l][d + c];
            ss += v * v;
        }
        ss += __shfl_xor(ss, 1, 64);
        ss += __shfl_xor(ss, 2, 64);
        ss += __shfl_xor(ss, 4, 64);
        ss += __shfl_xor(ss, 8, 64);
        if (c == 0) invn[l] = 1.0f / fmaxf(sqrtf(ss), 1e-12f);
    }
    __syncthreads();
    #pragma unroll
    for (int p = 0; p < 16; ++p) {
        int r = bi * 256 + l0 + p;
        F[(size_t)r * DIMS + tid] = f2bf(tile[p][tid] * invn[p]);
    }
}

// Register staging (replaces global_load_lds): load the 128x64 A/B panel pair
// into VGPRs (issued early, hidden under MFMA), ds_write late (T14 split).
// Byte-for-byte identical LDS image to R9's gload_lds version: thread chunk
// p = i*256+tid lands at linear LDS offset p*16, sourced from global chunk
// c = (p&7) ^ (row&7) of row p>>3 (XOR swizzle via source permutation).
__device__ inline void stage_load(const uint16_t* __restrict__ F, int k0,
                                  int rowA0, int rowB0, int tid,
                                  u32x4* ra, u32x4* rb) {
    #pragma unroll
    for (int i = 0; i < 4; ++i) {
        int p = i * 256 + tid;
        int row = p >> 3;
        int c = (p & 7) ^ (row & 7);
        ra[i] = *(const u32x4*)(F + (size_t)(rowA0 + row) * DIMS + k0 + c * 8);
        rb[i] = *(const u32x4*)(F + (size_t)(rowB0 + row) * DIMS + k0 + c * 8);
    }
}

__device__ inline void stage_write(char* smem, int buf, int tid,
                                   const u32x4* ra, const u32x4* rb) {
    #pragma unroll
    for (int i = 0; i < 4; ++i) {
        int p = i * 256 + tid;
        *(u32x4*)(smem + buf * 32768 + p * 16) = ra[i];
        *(u32x4*)(smem + buf * 32768 + 16384 + p * 16) = rb[i];
    }
}

// 128x128 tile of sims = F*F^T per block (4 waves, 2x2 quadrants), reg-staged
// double-buffered LDS, fused exp/weight epilogue, no atomics (den partials).
__global__ __launch_bounds__(256) void sim_kernel(const uint16_t* __restrict__ F,
                                                  float* __restrict__ den_part,
                                                  float* __restrict__ num) {
    __shared__ char smem[65536];
    const int tid = threadIdx.x;
    const int wid = tid >> 6;
    const int lane = tid & 63;
    const int lr = lane & 15;
    const int kg = lane >> 4;
    const int wr = wid >> 1, wc = wid & 1;

    const int bid = blockIdx.x;
    const int swz = (bid & 7) * 128 + (bid >> 3);  // XCD-aware, bijective (1024 = 8*128)
    const int bm = swz >> 5, bn = swz & 31;
    const int rowA0 = bm * 128, rowB0 = bn * 128;

    f32x4 acc[4][4];
    #pragma unroll
    for (int a = 0; a < 4; ++a)
        #pragma unroll
        for (int b = 0; b < 4; ++b) acc[a][b] = (f32x4){0.f, 0.f, 0.f, 0.f};

    u32x4 ra[4], rb[4];
    stage_load(F, 0, rowA0, rowB0, tid, ra, rb);
    stage_write(smem, 0, tid, ra, rb);
    __syncthreads();

    for (int t = 0; t < 4; ++t) {
        const int cur = t & 1;
        if (t < 3) stage_load(F, (t + 1) * 64, rowA0, rowB0, tid, ra, rb);  // issue early
        const char* Ab = smem + cur * 32768;
        const char* Bb = Ab + 16384;
        #pragma unroll
        for (int kk = 0; kk < 2; ++kk) {
            bf16x8 af[4], bfr[4];
            #pragma unroll
            for (int a = 0; a < 4; ++a) {
                int r = wr * 64 + a * 16 + lr;
                int pc = (kk * 4 + kg) ^ (r & 7);
                af[a] = *(const bf16x8*)(Ab + r * 128 + pc * 16);
            }
            #pragma unroll
            for (int b = 0; b < 4; ++b) {
                int r = wc * 64 + b * 16 + lr;
                int pc = (kk * 4 + kg) ^ (r & 7);
                bfr[b] = *(const bf16x8*)(Bb + r * 128 + pc * 16);
            }
            #pragma unroll
            for (int a = 0; a < 4; ++a)
                #pragma unroll
                for (int b = 0; b < 4; ++b)
                    acc[a][b] = __builtin_amdgcn_mfma_f32_16x16x32_bf16(af[a], bfr[b], acc[a][b], 0, 0, 0);
        }
        if (t < 3) stage_write(smem, cur ^ 1, tid, ra, rb);                 // write late
        __syncthreads();
    }

    const int i0 = rowA0 + wr * 64;
    const int j0 = rowB0 + wc * 64;
    const float K2 = 1.442695041f / 0.07f;            // exp(x/T) = exp2(x*K2)
    const float slope = 1.0f / (float)NNEIGH;
    const bool hasPartner = (((bn - bm) & 31) == 16); // only these tiles hold partner cols
    float srow[4][4];

    #pragma unroll
    for (int a = 0; a < 4; ++a)
        #pragma unroll
        for (int e = 0; e < 4; ++e) srow[a][e] = 0.f;

    #pragma unroll
    for (int a = 0; a < 4; ++a) {
        #pragma unroll
        for (int b = 0; b < 4; ++b) {
            const int col = j0 + b * 16 + lr;
            #pragma unroll
            for (int e = 0; e < 4; ++e) {
                const int row = i0 + a * 16 + kg * 4 + e;
                const int d = col - row;
                // w(d): 0 at d=0; right: min(d/30,1); left: min(~d/30,1); ~d == d^(d>>31)
                const int dm = d ^ (d >> 31);
                float wv = fminf((float)dm * slope, 1.0f);
                float v = exp2f(acc[a][b][e] * K2) * wv;
                srow[a][e] += v;
                if (hasPartner && ((d & (N_TOTAL - 1)) == M_HALF)) num[row] = v;
            }
        }
    }
    // reduce across the 16 lr lanes (cols of sub-tile)
    #pragma unroll
    for (int a = 0; a < 4; ++a)
        #pragma unroll
        for (int e = 0; e < 4; ++e) {
            float s = srow[a][e];
            s += __shfl_xor(s, 1, 64);
            s += __shfl_xor(s, 2, 64);
            s += __shfl_xor(s, 4, 64);
            s += __shfl_xor(s, 8, 64);
            srow[a][e] = s;
        }
    // combine the two column-waves (wc=0,1) per row in LDS, then plain store
    float* cmb = (float*)smem;   // [128 rows][2 wc]; safe: all LDS reads done
    if (lr == 0) {
        #pragma unroll
        for (int a = 0; a < 4; ++a)
            #pragma unroll
            for (int e = 0; e < 4; ++e)
                cmb[(wr * 64 + a * 16 + kg * 4 + e) * 2 + wc] = srow[a][e];
    }
    __syncthreads();
    if (tid < 128)
        den_part[(size_t)(rowA0 + tid) * NSLICE + bn] = cmb[tid * 2] + cmb[tid * 2 + 1];
}

// Sum the 32 den partials per row, form num/den, reduce to the scalar mean.
__global__ __launch_bounds__(1024) void fin_kernel(const float* __restrict__ num,
                                                   const float* __restrict__ den_part,
                                                   float* __restrict__ out) {
    __shared__ float sb[16];
    const int tid = threadIdx.x;
    float s = 0.f;
    #pragma unroll
    for (int i = 0; i < N_TOTAL / 1024; ++i) {
        int r = i * 1024 + tid;
        const f32x4* dp = (const f32x4*)(den_part + (size_t)r * NSLICE);
        f32x4 acc4 = dp[0];
        #pragma unroll
        for (int k = 1; k < NSLICE / 4; ++k) acc4 += dp[k];
        float den = acc4[0] + acc4[1] + acc4[2] + acc4[3];
        s += num[r] / den;
    }
    s += __shfl_xor(s, 1, 64);
    s += __shfl_xor(s, 2, 64);
    s += __shfl_xor(s, 4, 64);
    s += __shfl_xor(s, 8, 64);
    s += __shfl_xor(s, 16, 64);
    s += __shfl_xor(s, 32, 64);
    if ((tid & 63) == 0) sb[tid >> 6] = s;
    __syncthreads();
    if (tid == 0) {
        float t = 0.f;
        #pragma unroll
        for (int w = 0; w < 16; ++w) t += sb[w];
        out[0] = t * (1.0f / (float)N_TOTAL);
    }
}

extern "C" void kernel_launch(void* const* d_in, const int* in_sizes, int n_in,
                              void* d_out, int out_size, void* d_ws, size_t ws_size,
                              hipStream_t stream) {
    const float* emb = (const float*)d_in[0];
    // masks (d_in[1]) and labelvecs (d_in[2]) unused by the reference output
    uint16_t* F = (uint16_t*)d_ws;                                   // 2 MB
    float* num = (float*)((char*)d_ws + (size_t)N_TOTAL * DIMS * 2); // 16 KB
    float* den_part = num + N_TOTAL;                                 // 512 KB
    float* out = (float*)d_out;

    nt_kernel<<<dim3(256), dim3(256), 0, stream>>>(emb, F);
    sim_kernel<<<dim3(NTILES), dim3(256), 0, stream>>>(F, den_part, num);
    fin_kernel<<<dim3(1), dim3(1024), 0, stream>>>(num, den_part, out);
}